// Round 15
// baseline (1397.008 us; speedup 1.0000x reference)
//
#include <hip/hip_runtime.h>

// Binary op: gather-2 -> [32x64]@[64x512] + bias -> l2norm(d) -> scatter-store
// N_SYMBOLS=128, D_WORLDS=32, N_WORLDS=512, BATCH=2048, N_STEPS=8
// Floors: ~400 MB mandatory HBM -> ~64 us @ 6.3 TB/s; 2.1 G FMA -> ~27 us VALU.
//
// R14 = R2 design held stable (15th round without GPU; ledger complete).
// Baseline diagnosis: prior 1257us kernel's float4 acc[32] = 128-VGPR
// accumulator likely spilled to scratch -> 20x blowup. Scalar acc[32] (32
// VGPR) structurally eliminates that mode regardless of W-load strategy.
// Design under test:
//  - W[sym] wave-uniform -> uniform float4 loads should select s_load_dwordx4
//    into SGPRs; FMA = v_fmac_f32 v, s, v (1 SGPR operand: legal). Zero LDS.
//  - 1 column/thread (TPB=512), scalar acc[32] -> target <=64 VGPR -> 8 waves/SIMD.
//  - unroll-2 on k4 loops: 2 x-load quads in flight (8 VGPR); full unroll
//    adds 32 VGPR of live loads with no latency benefit at 8 waves/SIMD.
// Predictions: LDS=0, VGPR<=64, dur 1257 -> ~100-200 us. Worst case
// (promotion fails): uniform per-lane W loads are L1-hits, VMEM issue < VALU
// issue -> still VALU-bound near floor, ~120 VGPR, no spill.
// Failure reads: per-lane W loads in disasm => promotion failed (fallback:
// LDS-broadcast W); low VALU + low HBM% + slow => SMEM lgkmcnt serialization.

constexpr int D     = 32;    // D_WORLDS
constexpr int NW    = 512;   // N_WORLDS
constexpr int BATCH = 2048;
constexpr int TPB   = 512;   // 1 column per thread

__global__ __launch_bounds__(TPB) void binop_kernel(
    const float* __restrict__ states,   // [8*2048, 32, 512]
    const float* __restrict__ W,        // [128, 32, 64]
    const float* __restrict__ b,        // [128, 32]
    const int*   __restrict__ indices,  // [2048]
    const int*   __restrict__ symbols,  // [2048]
    const int*   __restrict__ args,     // [2048, 2]
    float*       __restrict__ out)      // [2048, 32, 512]
{
    const int n = blockIdx.x;
    const int t = threadIdx.x;

    // Force wave-uniform scalars into SGPRs so W/b reads scalarize to s_load.
    const int sym = __builtin_amdgcn_readfirstlane(symbols[n]);
    const int a0  = __builtin_amdgcn_readfirstlane(args[2 * n]);
    const int a1  = __builtin_amdgcn_readfirstlane(args[2 * n + 1]);
    const int idx = __builtin_amdgcn_readfirstlane(indices[n]);

    const float4* __restrict__ W4 = (const float4*)(W + (size_t)sym * (D * 2 * D)); // [32][16]
    const float*  __restrict__ br = b + (size_t)sym * D;                            // [32]

    const float* lp = states + (size_t)(a0 * BATCH + idx) * (D * NW) + t;
    const float* rp = states + (size_t)(a1 * BATCH + idx) * (D * NW) + t;

    float acc[D];
    #pragma unroll
    for (int d = 0; d < D; ++d) acc[d] = 0.f;

    // Row d of W[sym] is 64 floats = 16 float4; left half k4 in [0,8),
    // right half k4 in [8,16).

    // ---- left half: k in [0,32) ----
    #pragma unroll 2
    for (int k4 = 0; k4 < 8; ++k4) {
        const int k = k4 * 4;
        const float x0 = lp[(size_t)(k + 0) * NW];
        const float x1 = lp[(size_t)(k + 1) * NW];
        const float x2 = lp[(size_t)(k + 2) * NW];
        const float x3 = lp[(size_t)(k + 3) * NW];
        #pragma unroll
        for (int d = 0; d < D; ++d) {
            const float4 wv = W4[d * 16 + k4];          // uniform -> s_load_dwordx4
            acc[d] += wv.x * x0 + wv.y * x1 + wv.z * x2 + wv.w * x3;
        }
    }

    // ---- right half: k in [0,32) -> W columns [32,64) ----
    #pragma unroll 2
    for (int k4 = 0; k4 < 8; ++k4) {
        const int k = k4 * 4;
        const float x0 = rp[(size_t)(k + 0) * NW];
        const float x1 = rp[(size_t)(k + 1) * NW];
        const float x2 = rp[(size_t)(k + 2) * NW];
        const float x3 = rp[(size_t)(k + 3) * NW];
        #pragma unroll
        for (int d = 0; d < D; ++d) {
            const float4 wv = W4[d * 16 + 8 + k4];      // uniform -> s_load_dwordx4
            acc[d] += wv.x * x0 + wv.y * x1 + wv.z * x2 + wv.w * x3;
        }
    }

    // ---- bias + L2-normalize along d (thread owns all 32 d's of its column) ----
    float sq = 0.f;
    #pragma unroll
    for (int d = 0; d < D; ++d) {
        acc[d] += br[d];                 // uniform -> SGPR
        sq += acc[d] * acc[d];
    }
    const float sc = rsqrtf(fmaxf(sq, 1e-12f));

    float* op = out + (size_t)idx * (D * NW) + t;
    #pragma unroll
    for (int d = 0; d < D; ++d)
        op[(size_t)d * NW] = acc[d] * sc;
}

extern "C" void kernel_launch(void* const* d_in, const int* in_sizes, int n_in,
                              void* d_out, int out_size, void* d_ws, size_t ws_size,
                              hipStream_t stream) {
    const float* states  = (const float*)d_in[0];
    const float* W       = (const float*)d_in[1];
    const float* b       = (const float*)d_in[2];
    const int*   indices = (const int*)d_in[3];
    const int*   symbols = (const int*)d_in[4];
    const int*   args    = (const int*)d_in[5];
    float*       out     = (float*)d_out;

    binop_kernel<<<dim3(BATCH), dim3(TPB), 0, stream>>>(
        states, W, b, indices, symbols, args, out);
}